// Round 5
// baseline (390.701 us; speedup 1.0000x reference)
//
#include <hip/hip_runtime.h>
#include <math.h>

// DeepGCN layer, round 4b: f16 MFMA + algebraic reorder Â(hW) = (Âh)W.
//   k_ln1:    h = f16(gelu(LN1(nf)))                        [N,128] f16
//   k_gather: aggh = f16( dinv_d * (sum_e dinv_s h_s + dinv_d h_d) )
//   k_ffn:    conv = nf + (aggh @ Wc) + bc  (MFMA, fused)
//             LN2 -> stage1 (128->512, MFMA+gelu) -> stage2 (512->128, MFMA)
//             out = nf + gelu(.)
// MFMA 16x16x32 f16 layouts (dtype-independent, m89/m101):
//   A[m = lane&15][k = (lane>>4)*8 + j]   (half8)
//   B[k = (lane>>4)*8 + j][n = lane&15]
//   D[m = (lane>>4)*4 + r][n = lane&15]   (float4)
// N = 100000 (multiple of 32) -> exact grids, no bounds checks.

typedef _Float16 half8  __attribute__((ext_vector_type(8)));
typedef _Float16 half2v __attribute__((ext_vector_type(2)));
typedef __fp16   fp16x2 __attribute__((ext_vector_type(2)));
typedef float    floatx4 __attribute__((ext_vector_type(4)));

// tanh-form GELU: x*sigmoid(1.595769*(x+0.044715 x^3)); max abs err ~1e-3
__device__ __forceinline__ float gelu_f(float x){
  float x2 = x*x;
  float z  = x*(1.5957691216f + 0.07135481283f*x2);
  float e  = __expf(-z);
  return x * __builtin_amdgcn_rcpf(1.0f + e);
}
__device__ __forceinline__ unsigned pk16(float a, float b){   // 2x f32 -> packed f16 (RTZ), 1 VALU op
  fp16x2 h = __builtin_amdgcn_cvt_pkrtz(a, b);
  return __builtin_bit_cast(unsigned, h);
}
__device__ __forceinline__ float wave_reduce_sum(float v){
  #pragma unroll
  for (int off = 32; off > 0; off >>= 1) v += __shfl_xor(v, off, 64);
  return v;
}

// ---------------- graph prep ----------------
__global__ void k_init(int* incount, int N){
  int n = blockIdx.x*blockDim.x + threadIdx.x;
  if (n < N) incount[n] = 0;
}
__global__ void k_count(const int* __restrict__ ei, int* incount, int E){
  int e = blockIdx.x*blockDim.x + threadIdx.x;
  if (e < E) atomicAdd(&incount[ei[E + e]], 1);
}
__global__ void k_scanA(const int* __restrict__ incount, int* row_incl, int* blkSums, int N){
  __shared__ int wsum[4];
  int t = threadIdx.x, w = t >> 6, l = t & 63;
  int n = blockIdx.x*256 + t;
  int v = (n < N) ? incount[n] : 0;
  int x = v;
  #pragma unroll
  for (int off = 1; off < 64; off <<= 1){
    int y = __shfl_up(x, off);
    if (l >= off) x += y;
  }
  if (l == 63) wsum[w] = x;
  __syncthreads();
  if (t == 0){
    int s = 0;
    #pragma unroll
    for (int i = 0; i < 4; i++){ int c = wsum[i]; wsum[i] = s; s += c; }
  }
  __syncthreads();
  x += wsum[w];
  if (n < N) row_incl[n] = x;
  if (t == 255) blkSums[blockIdx.x] = x;
}
__global__ void k_scanB(const int* __restrict__ blkSums, int* blkOff, int nb){
  __shared__ int wsum[8];
  int t = threadIdx.x, w = t >> 6, l = t & 63;
  int v = (t < nb) ? blkSums[t] : 0;
  int x = v;
  #pragma unroll
  for (int off = 1; off < 64; off <<= 1){
    int y = __shfl_up(x, off);
    if (l >= off) x += y;
  }
  if (l == 63) wsum[w] = x;
  __syncthreads();
  if (t == 0){
    int s = 0;
    #pragma unroll
    for (int i = 0; i < 8; i++){ int c = wsum[i]; wsum[i] = s; s += c; }
  }
  __syncthreads();
  x += wsum[w];
  if (t < nb) blkOff[t] = x - v;
}
__global__ void k_scanC(const int* __restrict__ incount, const int* __restrict__ blkOff,
                        int* row_start, int* cursor, float* dinv, int N){
  int n = blockIdx.x*blockDim.x + threadIdx.x;
  if (n < N){
    int ic = incount[n];
    int rs = row_start[n] - ic + blkOff[n >> 8];
    row_start[n] = rs;
    cursor[n] = rs;
    dinv[n] = rsqrtf((float)ic + 1.0f);
  }
}
__global__ void k_fill(const int* __restrict__ ei, int* cursor, int* eSrc, int E){
  int e = blockIdx.x*blockDim.x + threadIdx.x;
  if (e < E){
    int s = ei[e], d = ei[E + e];
    int pos = atomicAdd(&cursor[d], 1);
    eSrc[pos] = s;
  }
}

// ---------------- unified weight pack: fp32 [K][Nc] -> B-frag-major f16 ----------------
// frag addr: P[((tile*(K/32)+kb)*64 + lane)*8 + j] = f16(W[kb*32+(lane>>4)*8+j][tile*16+(lane&15)])
__global__ void k_pack(const float* __restrict__ Wc, const float* __restrict__ W1,
                       const float* __restrict__ W2, _Float16* __restrict__ Wcp,
                       _Float16* __restrict__ W1p, _Float16* __restrict__ W2p){
  int id = blockIdx.x*256 + threadIdx.x;   // 18432 total
  const float* W; _Float16* P; int K, Nc, base;
  if (id < 2048)            { W = Wc; P = Wcp; K = 128; Nc = 128; base = id; }
  else if (id < 2048+8192)  { W = W1; P = W1p; K = 128; Nc = 512; base = id - 2048; }
  else                      { W = W2; P = W2p; K = 512; Nc = 128; base = id - 10240; }
  int lane = base & 63;
  int nkb  = K >> 5;
  int kb   = (base >> 6) % nkb;
  int tile = base / (nkb << 6);
  int col  = (tile << 4) + (lane & 15);
  int k0   = (kb << 5) + ((lane >> 4) << 3);
  _Float16 v[8];
  #pragma unroll
  for (int j = 0; j < 8; j++) v[j] = (_Float16)W[(size_t)(k0 + j)*Nc + col];
  *(half8*)&P[(size_t)base * 8] = *(const half8*)v;
}

// ---------------- h = f16(gelu(LN1(nf))) ----------------
__global__ __launch_bounds__(256) void k_ln1(const float* __restrict__ nf,
    const float* __restrict__ g, const float* __restrict__ b,
    _Float16* __restrict__ h, int N)
{
  int w = threadIdx.x >> 6, l = threadIdx.x & 63;
  int node = blockIdx.x*4 + w;
  float2 x = *(const float2*)&nf[(size_t)node*128 + 2*l];
  float mu = wave_reduce_sum(x.x + x.y) * 0.0078125f;
  float d0 = x.x - mu, d1 = x.y - mu;
  float var = wave_reduce_sum(d0*d0 + d1*d1) * 0.0078125f;
  float rs = rsqrtf(var + 1e-5f);
  float y0 = gelu_f(d0*rs*g[2*l]   + b[2*l]);
  float y1 = gelu_f(d1*rs*g[2*l+1] + b[2*l+1]);
  *(unsigned*)&h[(size_t)node*128 + 2*l] = pk16(y0, y1);
}

// ---------------- CSR gather over h: aggh f16 ----------------
__global__ __launch_bounds__(256) void k_gather(const _Float16* __restrict__ h,
    const int* __restrict__ eSrc, const int* __restrict__ row_start,
    const int* __restrict__ incount, const float* __restrict__ dinv,
    _Float16* __restrict__ aggh, int N)
{
  int w = threadIdx.x >> 6, l = threadIdx.x & 63;
  int node = (blockIdx.x << 2) + w;
  int g  = l >> 4;     // edge slot 0..3
  int li = l & 15;     // cols li*8 .. li*8+7
  float dn = dinv[node];
  int start = row_start[node], cnt = incount[node];
  float acc[8];
  #pragma unroll
  for (int i = 0; i < 8; i++) acc[i] = 0.f;
  // virtual edge 0 = self-loop
  for (int e = g; e < cnt + 1; e += 4){
    int s = (e == 0) ? node : eSrc[start + e - 1];
    float ds = dinv[s];
    uint4 v = *(const uint4*)&h[(size_t)s*128 + (li << 3)];
    half2v p0 = __builtin_bit_cast(half2v, v.x);
    half2v p1 = __builtin_bit_cast(half2v, v.y);
    half2v p2 = __builtin_bit_cast(half2v, v.z);
    half2v p3 = __builtin_bit_cast(half2v, v.w);
    acc[0] += ds*(float)p0.x; acc[1] += ds*(float)p0.y;
    acc[2] += ds*(float)p1.x; acc[3] += ds*(float)p1.y;
    acc[4] += ds*(float)p2.x; acc[5] += ds*(float)p2.y;
    acc[6] += ds*(float)p3.x; acc[7] += ds*(float)p3.y;
  }
  #pragma unroll
  for (int i = 0; i < 8; i++){
    acc[i] += __shfl_xor(acc[i], 16);
    acc[i] += __shfl_xor(acc[i], 32);
  }
  if (l < 16){
    uint4 o;
    o.x = pk16(dn*acc[0], dn*acc[1]);
    o.y = pk16(dn*acc[2], dn*acc[3]);
    o.z = pk16(dn*acc[4], dn*acc[5]);
    o.w = pk16(dn*acc[6], dn*acc[7]);
    *(uint4*)&aggh[(size_t)node*128 + (l << 3)] = o;
  }
}

// ---------------- fused conv-GEMM + LN2 + FFN ----------------
__global__ __launch_bounds__(256) void k_ffn(
    const float* __restrict__ nf, const _Float16* __restrict__ aggh,
    const _Float16* __restrict__ Wcp, const float* __restrict__ bc,
    const float* __restrict__ g2, const float* __restrict__ bl2,
    const _Float16* __restrict__ W1p, const float* __restrict__ b1,
    const _Float16* __restrict__ W2p, const float* __restrict__ b2,
    float* __restrict__ out, int N)
{
  // t_s[32][520] f16; c_s/f_s[32][136] aliases the front (dead before t_s writes)
  __shared__ __align__(16) unsigned short u_s[32*520];
  #define F_S(r,c) (*(_Float16*)&u_s[(r)*136 + (c)])
  #define T_S(r,c) (*(_Float16*)&u_s[(r)*520 + (c)])
  int t = threadIdx.x, w = t >> 6, l = t & 63;
  int nb = blockIdx.x << 5;
  int quad = l >> 4, ln16 = l & 15;

  // ---- phase A: conv = nf + (aggh @ Wc) + bc -> c_s (f16)
  {
    half8 ag[2][4];
    #pragma unroll
    for (int mt = 0; mt < 2; mt++)
      #pragma unroll
      for (int kb = 0; kb < 4; kb++)
        ag[mt][kb] = *(const half8*)&aggh[(size_t)(nb + (mt<<4) + ln16)*128 + (kb<<5) + (quad<<3)];
    const half8* Wp8 = (const half8*)Wcp;
    #pragma unroll
    for (int nt = 0; nt < 2; nt++){
      int tile = (w << 1) + nt;
      half8 bf[4];
      #pragma unroll
      for (int kb = 0; kb < 4; kb++) bf[kb] = Wp8[(size_t)((tile << 2) + kb)*64 + l];
      floatx4 acc0 = {0.f,0.f,0.f,0.f}, acc1 = {0.f,0.f,0.f,0.f};
      #pragma unroll
      for (int kb = 0; kb < 4; kb++){
        acc0 = __builtin_amdgcn_mfma_f32_16x16x32_f16(ag[0][kb], bf[kb], acc0, 0, 0, 0);
        acc1 = __builtin_amdgcn_mfma_f32_16x16x32_f16(ag[1][kb], bf[kb], acc1, 0, 0, 0);
      }
      int col = (tile << 4) + ln16;
      float bcv = bc[col];
      #pragma unroll
      for (int r = 0; r < 4; r++){
        int m0 = (quad << 2) + r;
        F_S(m0, col)      = (_Float16)(acc0[r] + nf[(size_t)(nb + m0)*128 + col] + bcv);
        F_S(m0 + 16, col) = (_Float16)(acc1[r] + nf[(size_t)(nb + m0 + 16)*128 + col] + bcv);
      }
    }
  }
  __syncthreads();

  // ---- phase B: LN2 in place on c_s -> f_s (f16)
  #pragma unroll
  for (int q = 0; q < 8; q++){
    int m = (w << 3) + q;
    unsigned pu = *(unsigned*)&u_s[m*136 + 2*l];
    half2v hp = __builtin_bit_cast(half2v, pu);
    float x0 = (float)hp.x, x1 = (float)hp.y;
    float mu = wave_reduce_sum(x0 + x1) * 0.0078125f;
    float d0 = x0 - mu, d1 = x1 - mu;
    float var = wave_reduce_sum(d0*d0 + d1*d1) * 0.0078125f;
    float rs = rsqrtf(var + 1e-5f);
    float y0 = d0*rs*g2[2*l]   + bl2[2*l];
    float y1 = d1*rs*g2[2*l+1] + bl2[2*l+1];
    *(unsigned*)&u_s[m*136 + 2*l] = pk16(y0, y1);
  }
  __syncthreads();

  // A-fragments into registers; f_s dead afterwards
  half8 a[2][4];
  #pragma unroll
  for (int mt = 0; mt < 2; mt++)
    #pragma unroll
    for (int kb = 0; kb < 4; kb++)
      a[mt][kb] = *(const half8*)&u_s[((mt << 4) + ln16)*136 + (kb << 5) + (quad << 3)];
  __syncthreads();

  // ---- stage 1: t = gelu(f @ W1 + b1) -> t_s f16. Wave w owns N-tiles [w*8, w*8+8).
  {
    const half8* Wp8 = (const half8*)W1p;
    #pragma unroll
    for (int nt = 0; nt < 8; nt++){
      int tile = (w << 3) + nt;
      half8 bf[4];
      #pragma unroll
      for (int kb = 0; kb < 4; kb++) bf[kb] = Wp8[(size_t)((tile << 2) + kb)*64 + l];
      floatx4 acc0 = {0.f,0.f,0.f,0.f}, acc1 = {0.f,0.f,0.f,0.f};
      #pragma unroll
      for (int kb = 0; kb < 4; kb++){
        acc0 = __builtin_amdgcn_mfma_f32_16x16x32_f16(a[0][kb], bf[kb], acc0, 0, 0, 0);
        acc1 = __builtin_amdgcn_mfma_f32_16x16x32_f16(a[1][kb], bf[kb], acc1, 0, 0, 0);
      }
      int col = (tile << 4) + ln16;
      float bv = b1[col];
      #pragma unroll
      for (int r = 0; r < 4; r++){
        T_S((quad << 2) + r, col)      = (_Float16)gelu_f(acc0[r] + bv);
        T_S(16 + (quad << 2) + r, col) = (_Float16)gelu_f(acc1[r] + bv);
      }
    }
  }
  __syncthreads();

  // ---- stage 2: f2 = gelu(t @ W2 + b2); out = nf + f2. Wave w owns N-tiles {2w, 2w+1}.
  {
    const half8* Wp8 = (const half8*)W2p;
    int tile0 = (w << 1), tile1 = tile0 + 1;
    floatx4 acc00 = {0.f,0.f,0.f,0.f}, acc01 = {0.f,0.f,0.f,0.f};
    floatx4 acc10 = {0.f,0.f,0.f,0.f}, acc11 = {0.f,0.f,0.f,0.f};
    for (int kb = 0; kb < 16; kb++){
      half8 a0 = *(const half8*)&u_s[ln16*520        + (kb << 5) + (quad << 3)];
      half8 a1 = *(const half8*)&u_s[(16 + ln16)*520 + (kb << 5) + (quad << 3)];
      half8 b0  = Wp8[(size_t)((tile0 << 4) + kb)*64 + l];
      half8 b1v = Wp8[(size_t)((tile1 << 4) + kb)*64 + l];
      acc00 = __builtin_amdgcn_mfma_f32_16x16x32_f16(a0, b0,  acc00, 0, 0, 0);
      acc01 = __builtin_amdgcn_mfma_f32_16x16x32_f16(a0, b1v, acc01, 0, 0, 0);
      acc10 = __builtin_amdgcn_mfma_f32_16x16x32_f16(a1, b0,  acc10, 0, 0, 0);
      acc11 = __builtin_amdgcn_mfma_f32_16x16x32_f16(a1, b1v, acc11, 0, 0, 0);
    }
    int col0 = (tile0 << 4) + ln16, col1 = (tile1 << 4) + ln16;
    float bv0 = b2[col0], bv1 = b2[col1];
    #pragma unroll
    for (int r = 0; r < 4; r++){
      size_t p0 = (size_t)(nb + (quad << 2) + r)*128;
      size_t p1 = p0 + 16*128;
      out[p0 + col0] = nf[p0 + col0] + gelu_f(acc00[r] + bv0);
      out[p0 + col1] = nf[p0 + col1] + gelu_f(acc01[r] + bv1);
      out[p1 + col0] = nf[p1 + col0] + gelu_f(acc10[r] + bv0);
      out[p1 + col1] = nf[p1 + col1] + gelu_f(acc11[r] + bv1);
    }
  }
  #undef F_S
  #undef T_S
}

extern "C" void kernel_launch(void* const* d_in, const int* in_sizes, int n_in,
                              void* d_out, int out_size, void* d_ws, size_t ws_size,
                              hipStream_t stream) {
  const float* nf   = (const float*)d_in[0];
  const int*   ei   = (const int*)  d_in[1];
  const float* ln1g = (const float*)d_in[3];
  const float* ln1b = (const float*)d_in[4];
  const float* Wc   = (const float*)d_in[5];
  const float* bc   = (const float*)d_in[6];
  const float* ln2g = (const float*)d_in[7];
  const float* ln2b = (const float*)d_in[8];
  const float* W1   = (const float*)d_in[9];
  const float* b1   = (const float*)d_in[10];
  const float* W2   = (const float*)d_in[11];
  const float* b2   = (const float*)d_in[12];
  float* out = (float*)d_out;

  int N = in_sizes[0] / 128;
  int E = in_sizes[1] / 2;

  char* ws = (char*)d_ws;
  _Float16* h    = (_Float16*)ws;                              // [N,128] f16
  _Float16* aggh = (_Float16*)(ws + (size_t)N*128*2);          // [N,128] f16
  char* p = ws + (size_t)N*128*4;
  p = (char*)(((size_t)p + 15) & ~(size_t)15);
  int*   incount   = (int*)p;   p += (size_t)N*4;
  float* dinv      = (float*)p; p += (size_t)N*4;
  int*   row_start = (int*)p;   p += (size_t)N*4;
  int*   cursor    = (int*)p;   p += (size_t)N*4;
  int*   eSrc      = (int*)p;   p += (size_t)E*4;
  int*   blkSums   = (int*)p;   p += 2048;
  int*   blkOff    = (int*)p;   p += 2048;
  p = (char*)(((size_t)p + 15) & ~(size_t)15);
  _Float16* Wcp = (_Float16*)p; p += (size_t)2048*8*2;    // 32 KB
  _Float16* W1p = (_Float16*)p; p += (size_t)8192*8*2;    // 128 KB
  _Float16* W2p = (_Float16*)p; p += (size_t)8192*8*2;    // 128 KB

  int SB = (N + 255) / 256;   // 391 for N=100000

  k_init <<<(N+255)/256, 256, 0, stream>>>(incount, N);
  k_count<<<(E+255)/256, 256, 0, stream>>>(ei, incount, E);
  k_scanA<<<SB, 256, 0, stream>>>(incount, row_start, blkSums, N);
  k_scanB<<<1, 512, 0, stream>>>(blkSums, blkOff, SB);
  k_scanC<<<(N+255)/256, 256, 0, stream>>>(incount, blkOff, row_start, cursor, dinv, N);
  k_fill <<<(E+255)/256, 256, 0, stream>>>(ei, cursor, eSrc, E);

  k_pack<<<72, 256, 0, stream>>>(Wc, W1, W2, Wcp, W1p, W2p);
  k_ln1 <<<N/4, 256, 0, stream>>>(nf, ln1g, ln1b, h, N);
  k_gather<<<N/4, 256, 0, stream>>>(h, eSrc, row_start, incount, dinv, aggh, N);
  k_ffn <<<N/32, 256, 0, stream>>>(nf, aggh, Wcp, bc, ln2g, ln2b, W1p, b1, W2p, b2, out, N);
}

// Round 6
// 359.497 us; speedup vs baseline: 1.0868x; 1.0868x over previous
//
#include <hip/hip_runtime.h>
#include <math.h>

// DeepGCN layer, round 6: f16 MFMA, reorder Â(hW)=(Âh)W, coalesced k_ffn.
//   memset:  incount = 0
//   k_count/scanA/scanB/scanC/k_fill: CSR-by-dst build
//   k_prep:  blocks 0..71 pack weights -> B-frag f16; rest: h = f16(gelu(LN1(nf)))
//   k_gather: aggh = f16( dinv_d*(sum_e dinv_s h_s + dinv_d h_d) )  [8 slots/wave]
//   k_ffn:   LDS-staged aggh -> conv MFMA -> +nf (coalesced, regs) -> LN2
//            -> stage1 (128->512 MFMA + gelu) -> stage2 (512->128 MFMA)
//            -> LDS round-trip -> coalesced residual epilogue
// MFMA 16x16x32 f16 layouts (dtype-independent, m89/m101):
//   A[m = lane&15][k = (lane>>4)*8 + j]   (half8)
//   B[k = (lane>>4)*8 + j][n = lane&15]
//   D[m = (lane>>4)*4 + r][n = lane&15]   (float4)
// N = 100000 (multiple of 32) -> exact grids, no bounds checks.

typedef _Float16 half8  __attribute__((ext_vector_type(8)));
typedef _Float16 half2v __attribute__((ext_vector_type(2)));
typedef __fp16   fp16x2 __attribute__((ext_vector_type(2)));
typedef float    floatx4 __attribute__((ext_vector_type(4)));

// tanh-form GELU: x*sigmoid(1.595769*(x+0.044715 x^3)); max abs err ~1e-3
__device__ __forceinline__ float gelu_f(float x){
  float x2 = x*x;
  float z  = x*(1.5957691216f + 0.07135481283f*x2);
  float e  = __expf(-z);
  return x * __builtin_amdgcn_rcpf(1.0f + e);
}
__device__ __forceinline__ unsigned pk16(float a, float b){   // 2x f32 -> packed f16 (RTZ)
  fp16x2 h = __builtin_amdgcn_cvt_pkrtz(a, b);
  return __builtin_bit_cast(unsigned, h);
}
__device__ __forceinline__ float wave_reduce_sum(float v){
  #pragma unroll
  for (int off = 32; off > 0; off >>= 1) v += __shfl_xor(v, off, 64);
  return v;
}

// ---------------- graph prep ----------------
__global__ void k_count(const int* __restrict__ ei, int* incount, int E){
  int e = blockIdx.x*blockDim.x + threadIdx.x;
  if (e < E) atomicAdd(&incount[ei[E + e]], 1);
}
__global__ void k_scanA(const int* __restrict__ incount, int* row_incl, int* blkSums, int N){
  __shared__ int wsum[4];
  int t = threadIdx.x, w = t >> 6, l = t & 63;
  int n = blockIdx.x*256 + t;
  int v = (n < N) ? incount[n] : 0;
  int x = v;
  #pragma unroll
  for (int off = 1; off < 64; off <<= 1){
    int y = __shfl_up(x, off);
    if (l >= off) x += y;
  }
  if (l == 63) wsum[w] = x;
  __syncthreads();
  if (t == 0){
    int s = 0;
    #pragma unroll
    for (int i = 0; i < 4; i++){ int c = wsum[i]; wsum[i] = s; s += c; }
  }
  __syncthreads();
  x += wsum[w];
  if (n < N) row_incl[n] = x;
  if (t == 255) blkSums[blockIdx.x] = x;
}
__global__ void k_scanB(const int* __restrict__ blkSums, int* blkOff, int nb){
  __shared__ int wsum[8];
  int t = threadIdx.x, w = t >> 6, l = t & 63;
  int v = (t < nb) ? blkSums[t] : 0;
  int x = v;
  #pragma unroll
  for (int off = 1; off < 64; off <<= 1){
    int y = __shfl_up(x, off);
    if (l >= off) x += y;
  }
  if (l == 63) wsum[w] = x;
  __syncthreads();
  if (t == 0){
    int s = 0;
    #pragma unroll
    for (int i = 0; i < 8; i++){ int c = wsum[i]; wsum[i] = s; s += c; }
  }
  __syncthreads();
  x += wsum[w];
  if (t < nb) blkOff[t] = x - v;
}
__global__ void k_scanC(const int* __restrict__ incount, const int* __restrict__ blkOff,
                        int* row_start, int* cursor, float* dinv, int N){
  int n = blockIdx.x*blockDim.x + threadIdx.x;
  if (n < N){
    int ic = incount[n];
    int rs = row_start[n] - ic + blkOff[n >> 8];
    row_start[n] = rs;
    cursor[n] = rs;
    dinv[n] = rsqrtf((float)ic + 1.0f);
  }
}
__global__ void k_fill(const int* __restrict__ ei, int* cursor, int* eSrc, int E){
  int e = blockIdx.x*blockDim.x + threadIdx.x;
  if (e < E){
    int s = ei[e], d = ei[E + e];
    int pos = atomicAdd(&cursor[d], 1);
    eSrc[pos] = s;
  }
}

// ---------------- k_prep: weight pack (blocks 0..71) + LN1/gelu (rest) ----------------
// pack: P[((tile*(K/32)+kb)*64+lane)*8+j] = f16(W[kb*32+(lane>>4)*8+j][tile*16+(lane&15)])
__global__ __launch_bounds__(256) void k_prep(
    const float* __restrict__ Wc, const float* __restrict__ W1, const float* __restrict__ W2,
    _Float16* __restrict__ Wcp, _Float16* __restrict__ W1p, _Float16* __restrict__ W2p,
    const float* __restrict__ nf, const float* __restrict__ g, const float* __restrict__ b,
    _Float16* __restrict__ h)
{
  int bid = blockIdx.x;
  if (bid < 72){
    int id = bid*256 + threadIdx.x;   // 18432 total
    const float* W; _Float16* P; int K, Nc, base;
    if (id < 2048)            { W = Wc; P = Wcp; K = 128; Nc = 128; base = id; }
    else if (id < 2048+8192)  { W = W1; P = W1p; K = 128; Nc = 512; base = id - 2048; }
    else                      { W = W2; P = W2p; K = 512; Nc = 128; base = id - 10240; }
    int lane = base & 63;
    int nkb  = K >> 5;
    int kb   = (base >> 6) % nkb;
    int tile = base / (nkb << 6);
    int col  = (tile << 4) + (lane & 15);
    int k0   = (kb << 5) + ((lane >> 4) << 3);
    _Float16 v[8];
    #pragma unroll
    for (int j = 0; j < 8; j++) v[j] = (_Float16)W[(size_t)(k0 + j)*Nc + col];
    *(half8*)&P[(size_t)base * 8] = *(const half8*)v;
  } else {
    int w = threadIdx.x >> 6, l = threadIdx.x & 63;
    int node = (bid - 72)*4 + w;
    float2 x = *(const float2*)&nf[(size_t)node*128 + 2*l];
    float mu = wave_reduce_sum(x.x + x.y) * 0.0078125f;
    float d0 = x.x - mu, d1 = x.y - mu;
    float var = wave_reduce_sum(d0*d0 + d1*d1) * 0.0078125f;
    float rs = rsqrtf(var + 1e-5f);
    float y0 = gelu_f(d0*rs*g[2*l]   + b[2*l]);
    float y1 = gelu_f(d1*rs*g[2*l+1] + b[2*l+1]);
    *(unsigned*)&h[(size_t)node*128 + 2*l] = pk16(y0, y1);
  }
}

// ---------------- CSR gather over h: 8 edge-slots per wave ----------------
__global__ __launch_bounds__(256) void k_gather(const _Float16* __restrict__ h,
    const int* __restrict__ eSrc, const int* __restrict__ row_start,
    const int* __restrict__ incount, const float* __restrict__ dinv,
    _Float16* __restrict__ aggh, int N)
{
  int w = threadIdx.x >> 6, l = threadIdx.x & 63;
  int node = (blockIdx.x << 2) + w;
  int g  = l >> 3;     // edge slot 0..7
  int li = l & 7;      // 32B chunk: cols li*16 .. li*16+15
  float dn = dinv[node];
  int start = row_start[node], cnt = incount[node];
  float acc[16];
  #pragma unroll
  for (int i = 0; i < 16; i++) acc[i] = 0.f;
  // virtual edge 0 = self-loop
  for (int e = g; e < cnt + 1; e += 8){
    int s = (e == 0) ? node : eSrc[start + e - 1];
    float ds = dinv[s];
    const uint4* hp = (const uint4*)&h[(size_t)s*128 + (li << 4)];
    uint4 v0 = hp[0], v1 = hp[1];
    half2v p0 = __builtin_bit_cast(half2v, v0.x), p1 = __builtin_bit_cast(half2v, v0.y);
    half2v p2 = __builtin_bit_cast(half2v, v0.z), p3 = __builtin_bit_cast(half2v, v0.w);
    half2v p4 = __builtin_bit_cast(half2v, v1.x), p5 = __builtin_bit_cast(half2v, v1.y);
    half2v p6 = __builtin_bit_cast(half2v, v1.z), p7 = __builtin_bit_cast(half2v, v1.w);
    acc[0] += ds*(float)p0.x; acc[1] += ds*(float)p0.y;
    acc[2] += ds*(float)p1.x; acc[3] += ds*(float)p1.y;
    acc[4] += ds*(float)p2.x; acc[5] += ds*(float)p2.y;
    acc[6] += ds*(float)p3.x; acc[7] += ds*(float)p3.y;
    acc[8]  += ds*(float)p4.x; acc[9]  += ds*(float)p4.y;
    acc[10] += ds*(float)p5.x; acc[11] += ds*(float)p5.y;
    acc[12] += ds*(float)p6.x; acc[13] += ds*(float)p6.y;
    acc[14] += ds*(float)p7.x; acc[15] += ds*(float)p7.y;
  }
  #pragma unroll
  for (int i = 0; i < 16; i++){
    acc[i] += __shfl_xor(acc[i], 8);
    acc[i] += __shfl_xor(acc[i], 16);
    acc[i] += __shfl_xor(acc[i], 32);
  }
  if (l < 8){
    uint4 o0, o1;
    o0.x = pk16(dn*acc[0],  dn*acc[1]);  o0.y = pk16(dn*acc[2],  dn*acc[3]);
    o0.z = pk16(dn*acc[4],  dn*acc[5]);  o0.w = pk16(dn*acc[6],  dn*acc[7]);
    o1.x = pk16(dn*acc[8],  dn*acc[9]);  o1.y = pk16(dn*acc[10], dn*acc[11]);
    o1.z = pk16(dn*acc[12], dn*acc[13]); o1.w = pk16(dn*acc[14], dn*acc[15]);
    uint4* op = (uint4*)&aggh[(size_t)node*128 + (l << 4)];
    op[0] = o0; op[1] = o1;
  }
}

// ---------------- fused conv-GEMM + LN2 + FFN, all coalesced ----------------
// LDS map (u_s, 33280 B):
//   [0, 4352)      shorts: F16 conv/LN2 result, stride 136 (f16)
//   [4352, 8704)   shorts: aggh stage, stride 136 (f16)
//   t_s: full u_s, stride 520 (f16)            [after F16 frags consumed]
//   fs : full u_s as float, stride 132 (fp32)  [after t_s consumed]
__global__ __launch_bounds__(256) void k_ffn(
    const float* __restrict__ nf, const _Float16* __restrict__ aggh,
    const _Float16* __restrict__ Wcp, const float* __restrict__ bc,
    const float* __restrict__ g2, const float* __restrict__ bl2,
    const _Float16* __restrict__ W1p, const float* __restrict__ b1,
    const _Float16* __restrict__ W2p, const float* __restrict__ b2,
    float* __restrict__ out, int N)
{
  __shared__ __align__(16) unsigned short u_s[32*520];
  int t = threadIdx.x, w = t >> 6, l = t & 63;
  int nb = blockIdx.x << 5;
  int quad = l >> 4, ln16 = l & 15;

  // ---- A0: stage aggh coalesced -> LDS stride-136 region
  {
    int m = t >> 3, c0 = (t & 7) << 4;           // row m, 32B chunk c0
    const uint4* src = (const uint4*)&aggh[(size_t)(nb + m)*128 + c0];
    uint4 v0 = src[0], v1 = src[1];
    uint4* dst = (uint4*)&u_s[4352 + m*136 + c0];
    dst[0] = v0; dst[1] = v1;
  }
  __syncthreads();

  // ---- A: conv MFMA; write (aggW + bc) f16 -> F16 region
  {
    half8 ag[2][4];
    #pragma unroll
    for (int mt = 0; mt < 2; mt++)
      #pragma unroll
      for (int kb = 0; kb < 4; kb++)
        ag[mt][kb] = *(const half8*)&u_s[4352 + ((mt << 4) + ln16)*136 + (kb << 5) + (quad << 3)];
    const half8* Wp8 = (const half8*)Wcp;
    #pragma unroll
    for (int nt = 0; nt < 2; nt++){
      int tile = (w << 1) + nt;
      half8 bf[4];
      #pragma unroll
      for (int kb = 0; kb < 4; kb++) bf[kb] = Wp8[(size_t)((tile << 2) + kb)*64 + l];
      floatx4 acc0 = {0.f,0.f,0.f,0.f}, acc1 = {0.f,0.f,0.f,0.f};
      #pragma unroll
      for (int kb = 0; kb < 4; kb++){
        acc0 = __builtin_amdgcn_mfma_f32_16x16x32_f16(ag[0][kb], bf[kb], acc0, 0, 0, 0);
        acc1 = __builtin_amdgcn_mfma_f32_16x16x32_f16(ag[1][kb], bf[kb], acc1, 0, 0, 0);
      }
      int col = (tile << 4) + ln16;
      float bcv = bc[col];
      #pragma unroll
      for (int r = 0; r < 4; r++){
        int m0 = (quad << 2) + r;
        *(_Float16*)&u_s[m0*136 + col]        = (_Float16)(acc0[r] + bcv);
        *(_Float16*)&u_s[(m0 + 16)*136 + col] = (_Float16)(acc1[r] + bcv);
      }
    }
  }
  __syncthreads();

  // ---- B: LN2 on (F16 + nf), coalesced; nf kept in registers
  float2 nfr[8];
  #pragma unroll
  for (int q = 0; q < 8; q++){
    int m = (w << 3) + q;
    unsigned pu = *(unsigned*)&u_s[m*136 + 2*l];
    half2v hp = __builtin_bit_cast(half2v, pu);
    nfr[q] = *(const float2*)&nf[(size_t)(nb + m)*128 + 2*l];
    float x0 = (float)hp.x + nfr[q].x;
    float x1 = (float)hp.y + nfr[q].y;
    float mu = wave_reduce_sum(x0 + x1) * 0.0078125f;
    float d0 = x0 - mu, d1 = x1 - mu;
    float var = wave_reduce_sum(d0*d0 + d1*d1) * 0.0078125f;
    float rs = rsqrtf(var + 1e-5f);
    float y0 = d0*rs*g2[2*l]   + bl2[2*l];
    float y1 = d1*rs*g2[2*l+1] + bl2[2*l+1];
    *(unsigned*)&u_s[m*136 + 2*l] = pk16(y0, y1);
  }
  __syncthreads();

  // A-fragments into registers; F16 region dead afterwards
  half8 a[2][4];
  #pragma unroll
  for (int mt = 0; mt < 2; mt++)
    #pragma unroll
    for (int kb = 0; kb < 4; kb++)
      a[mt][kb] = *(const half8*)&u_s[((mt << 4) + ln16)*136 + (kb << 5) + (quad << 3)];
  __syncthreads();

  // ---- stage 1: t = gelu(f @ W1 + b1) -> t_s (stride 520). Wave w: N-tiles [8w, 8w+8).
  {
    const half8* Wp8 = (const half8*)W1p;
    #pragma unroll
    for (int nt = 0; nt < 8; nt++){
      int tile = (w << 3) + nt;
      half8 bf[4];
      #pragma unroll
      for (int kb = 0; kb < 4; kb++) bf[kb] = Wp8[(size_t)((tile << 2) + kb)*64 + l];
      floatx4 acc0 = {0.f,0.f,0.f,0.f}, acc1 = {0.f,0.f,0.f,0.f};
      #pragma unroll
      for (int kb = 0; kb < 4; kb++){
        acc0 = __builtin_amdgcn_mfma_f32_16x16x32_f16(a[0][kb], bf[kb], acc0, 0, 0, 0);
        acc1 = __builtin_amdgcn_mfma_f32_16x16x32_f16(a[1][kb], bf[kb], acc1, 0, 0, 0);
      }
      int col = (tile << 4) + ln16;
      float bv = b1[col];
      #pragma unroll
      for (int r = 0; r < 4; r++){
        *(_Float16*)&u_s[((quad << 2) + r)*520 + col]      = (_Float16)gelu_f(acc0[r] + bv);
        *(_Float16*)&u_s[(16 + (quad << 2) + r)*520 + col] = (_Float16)gelu_f(acc1[r] + bv);
      }
    }
  }
  __syncthreads();

  // ---- stage 2: f2 = gelu(t @ W2 + b2). Wave w: N-tiles {2w, 2w+1}.
  floatx4 acc00 = {0.f,0.f,0.f,0.f}, acc01 = {0.f,0.f,0.f,0.f};
  floatx4 acc10 = {0.f,0.f,0.f,0.f}, acc11 = {0.f,0.f,0.f,0.f};
  int tile0 = (w << 1), tile1 = tile0 + 1;
  {
    const half8* Wp8 = (const half8*)W2p;
    for (int kb = 0; kb < 16; kb++){
      half8 a0 = *(const half8*)&u_s[ln16*520        + (kb << 5) + (quad << 3)];
      half8 a1 = *(const half8*)&u_s[(16 + ln16)*520 + (kb << 5) + (quad << 3)];
      half8 b0  = Wp8[(size_t)((tile0 << 4) + kb)*64 + l];
      half8 b1v = Wp8[(size_t)((tile1 << 4) + kb)*64 + l];
      acc00 = __builtin_amdgcn_mfma_f32_16x16x32_f16(a0, b0,  acc00, 0, 0, 0);
      acc01 = __builtin_amdgcn_mfma_f32_16x16x32_f16(a0, b1v, acc01, 0, 0, 0);
      acc10 = __builtin_amdgcn_mfma_f32_16x16x32_f16(a1, b0,  acc10, 0, 0, 0);
      acc11 = __builtin_amdgcn_mfma_f32_16x16x32_f16(a1, b1v, acc11, 0, 0, 0);
    }
  }
  __syncthreads();   // all t_s reads done; u_s reusable as fp32

  // ---- write f2 to LDS (fp32, stride 132), D-layout
  {
    float* fs = (float*)u_s;
    int col0 = (tile0 << 4) + ln16, col1 = (tile1 << 4) + ln16;
    float bv0 = b2[col0], bv1 = b2[col1];
    #pragma unroll
    for (int r = 0; r < 4; r++){
      int m0 = (quad << 2) + r;
      fs[m0*132 + col0]        = gelu_f(acc00[r] + bv0);
      fs[m0*132 + col1]        = gelu_f(acc01[r] + bv1);
      fs[(m0 + 16)*132 + col0] = gelu_f(acc10[r] + bv0);
      fs[(m0 + 16)*132 + col1] = gelu_f(acc11[r] + bv1);
    }
  }
  __syncthreads();

  // ---- coalesced residual epilogue: out = nf + f2
  {
    const float* fs = (const float*)u_s;
    #pragma unroll
    for (int q = 0; q < 8; q++){
      int m = (w << 3) + q;
      float2 o;
      o.x = nfr[q].x + fs[m*132 + 2*l];
      o.y = nfr[q].y + fs[m*132 + 2*l + 1];
      *(float2*)&out[(size_t)(nb + m)*128 + 2*l] = o;
    }
  }
}

extern "C" void kernel_launch(void* const* d_in, const int* in_sizes, int n_in,
                              void* d_out, int out_size, void* d_ws, size_t ws_size,
                              hipStream_t stream) {
  const float* nf   = (const float*)d_in[0];
  const int*   ei   = (const int*)  d_in[1];
  const float* ln1g = (const float*)d_in[3];
  const float* ln1b = (const float*)d_in[4];
  const float* Wc   = (const float*)d_in[5];
  const float* bc   = (const float*)d_in[6];
  const float* ln2g = (const float*)d_in[7];
  const float* ln2b = (const float*)d_in[8];
  const float* W1   = (const float*)d_in[9];
  const float* b1   = (const float*)d_in[10];
  const float* W2   = (const float*)d_in[11];
  const float* b2   = (const float*)d_in[12];
  float* out = (float*)d_out;

  int N = in_sizes[0] / 128;
  int E = in_sizes[1] / 2;

  char* ws = (char*)d_ws;
  _Float16* h    = (_Float16*)ws;                              // [N,128] f16
  _Float16* aggh = (_Float16*)(ws + (size_t)N*128*2);          // [N,128] f16
  char* p = ws + (size_t)N*128*4;
  p = (char*)(((size_t)p + 15) & ~(size_t)15);
  int*   incount   = (int*)p;   p += (size_t)N*4;
  float* dinv      = (float*)p; p += (size_t)N*4;
  int*   row_start = (int*)p;   p += (size_t)N*4;
  int*   cursor    = (int*)p;   p += (size_t)N*4;
  int*   eSrc      = (int*)p;   p += (size_t)E*4;
  int*   blkSums   = (int*)p;   p += 2048;
  int*   blkOff    = (int*)p;   p += 2048;
  p = (char*)(((size_t)p + 15) & ~(size_t)15);
  _Float16* Wcp = (_Float16*)p; p += (size_t)2048*8*2;    // 32 KB
  _Float16* W1p = (_Float16*)p; p += (size_t)8192*8*2;    // 128 KB
  _Float16* W2p = (_Float16*)p; p += (size_t)8192*8*2;    // 128 KB

  int SB = (N + 255) / 256;   // 391 for N=100000

  hipMemsetAsync(incount, 0, (size_t)N*4, stream);
  k_count<<<(E+255)/256, 256, 0, stream>>>(ei, incount, E);
  k_scanA<<<SB, 256, 0, stream>>>(incount, row_start, blkSums, N);
  k_scanB<<<1, 512, 0, stream>>>(blkSums, blkOff, SB);
  k_scanC<<<(N+255)/256, 256, 0, stream>>>(incount, blkOff, row_start, cursor, dinv, N);
  k_fill <<<(E+255)/256, 256, 0, stream>>>(ei, cursor, eSrc, E);

  k_prep<<<72 + N/4, 256, 0, stream>>>(Wc, W1, W2, Wcp, W1p, W2p, nf, ln1g, ln1b, h);
  k_gather<<<N/4, 256, 0, stream>>>(h, eSrc, row_start, incount, dinv, aggh, N);
  k_ffn <<<N/32, 256, 0, stream>>>(nf, aggh, Wcp, bc, ln2g, ln2b, W1p, b1, W2p, b2, out, N);
}